// Round 6
// baseline (1195.798 us; speedup 1.0000x reference)
//
#include <hip/hip_runtime.h>
#include <hip/hip_bf16.h>

typedef __bf16 bf8_t __attribute__((ext_vector_type(8)));
typedef float  f32x4 __attribute__((ext_vector_type(4)));

constexpr int N_NODES = 100000;
constexpr int E_ORIG  = 600000;
constexpr int E_LINE  = 1200000;

static inline int cdiv(int a, int b) { return (a + b - 1) / b; }

enum { A_AGG = 1, A_PAIR = 2 };

// ---- f32 -> bf16 pack (x_orig once) ----
__global__ void k_f2b(const float* __restrict__ X, __bf16* __restrict__ O, int n8) {
    int i = blockIdx.x * 256 + threadIdx.x;
    if (i >= n8) return;
    float4 a = ((const float4*)X)[2 * i], b = ((const float4*)X)[2 * i + 1];
    bf8_t o;
    o[0] = (__bf16)a.x; o[1] = (__bf16)a.y; o[2] = (__bf16)a.z; o[3] = (__bf16)a.w;
    o[4] = (__bf16)b.x; o[5] = (__bf16)b.y; o[6] = (__bf16)b.z; o[7] = (__bf16)b.w;
    ((bf8_t*)O)[i] = o;
}

// ---- CSR build: histogram ----
__global__ void k_hist(const int* __restrict__ dst, int* __restrict__ cnt, int E) {
    int e = blockIdx.x * 256 + threadIdx.x;
    if (e < E) atomicAdd(&cnt[dst[e]], 1);
}

// ---- CSR build: 3-phase exclusive scan over cnt[n] ----
__global__ void k_scan1(const int* __restrict__ cnt, int* __restrict__ offs,
                        int* __restrict__ bsum, int n) {
    __shared__ int tmp[256];
    int i = blockIdx.x * 256 + threadIdx.x;
    int v = (i < n) ? cnt[i] : 0;
    tmp[threadIdx.x] = v; __syncthreads();
    #pragma unroll
    for (int d = 1; d < 256; d <<= 1) {
        int t = (threadIdx.x >= d) ? tmp[threadIdx.x - d] : 0;
        __syncthreads();
        tmp[threadIdx.x] += t;
        __syncthreads();
    }
    if (i < n) offs[i] = tmp[threadIdx.x] - v;      // exclusive within block
    if (threadIdx.x == 255) bsum[blockIdx.x] = tmp[255];
}

__global__ void k_scan2(int* __restrict__ bsum, int nb) {
    __shared__ int tmp[256];
    __shared__ int carry;
    if (threadIdx.x == 0) carry = 0;
    __syncthreads();
    for (int base = 0; base < nb; base += 256) {
        int i = base + threadIdx.x;
        int v = (i < nb) ? bsum[i] : 0;
        tmp[threadIdx.x] = v; __syncthreads();
        #pragma unroll
        for (int d = 1; d < 256; d <<= 1) {
            int t = (threadIdx.x >= d) ? tmp[threadIdx.x - d] : 0;
            __syncthreads();
            tmp[threadIdx.x] += t;
            __syncthreads();
        }
        int tot = tmp[255];
        if (i < nb) bsum[i] = tmp[threadIdx.x] - v + carry;
        __syncthreads();
        if (threadIdx.x == 0) carry += tot;
        __syncthreads();
    }
}

__global__ void k_scan3(int* __restrict__ offs, int* __restrict__ cur,
                        const int* __restrict__ bsum, int n) {
    int i = blockIdx.x * 256 + threadIdx.x;
    if (i >= n) return;
    int o = offs[i] + bsum[blockIdx.x];
    offs[i] = o;
    cur[i]  = o;
}

// ---- CSR build: bucket fill ----
__global__ void k_fill(const int* __restrict__ src, const int* __restrict__ dst,
                       int* __restrict__ cur, int* __restrict__ adj, int E) {
    int e = blockIdx.x * 256 + threadIdx.x;
    if (e >= E) return;
    int p = atomicAdd(&cur[dst[e]], 1);
    adj[p] = src[e];
}

// ---- one-time weight pre-pack: f32 [128][NC] -> bf16 fragment-major ----
// frag(c,s): lane l, elem j  <- W[k = s*32 + (l>>4)*8 + j][n = c*16 + (l&15)]
struct WPtrs { const float* p[11]; int nc[11]; };

__global__ void k_packW(WPtrs wp, __bf16* __restrict__ out) {
    const float* W = wp.p[blockIdx.x];
    const int NC = wp.nc[blockIdx.x];
    __bf16* O = out + (size_t)blockIdx.x * 16384;
    const float4* W4 = (const float4*)W;
    const int tot = 32 * NC;                       // float4 count
    for (int e = threadIdx.x; e < tot; e += 256) {
        float4 w = W4[e];
        unsigned flat = (unsigned)e * 4;
        unsigned k = flat / NC, n = flat % NC;     // 4 consecutive n share k
        unsigned c = n >> 4, s = k >> 5, hi = (k >> 3) & 3, j = k & 7;
        unsigned l0 = (hi << 4) | (n & 15);
        unsigned base = ((c * 4 + s) * 64 + l0) * 8 + j;
        O[base]      = (__bf16)w.x;
        O[base + 8]  = (__bf16)w.y;
        O[base + 16] = (__bf16)w.z;
        O[base + 24] = (__bf16)w.w;
    }
}

// ============ fused multi-stage GIN layer building blocks ============
// sA: [128][128] bf16, swizzle: element col of row rl lives at
//     rl*128 + (((col>>3) ^ (rl&7))<<3) + (col&7)

template<int NT>
__device__ __forceinline__ void mm_from_lds(const __bf16* sA, const __bf16* __restrict__ Wp,
                                            int wv, int lane, f32x4 (&acc)[2][NT]) {
    const int m0 = lane & 15, kq = lane >> 4;
    #pragma unroll
    for (int s = 0; s < 4; ++s) {
        bf8_t fa[2];
        #pragma unroll
        for (int rt = 0; rt < 2; ++rt) {
            int rl = wv * 32 + rt * 16 + m0;
            int chunk = s * 4 + kq;
            fa[rt] = *(const bf8_t*)&sA[rl * 128 + ((chunk ^ (rl & 7)) << 3)];
        }
        #pragma unroll
        for (int ct = 0; ct < NT; ++ct) {
            bf8_t fw = *(const bf8_t*)(Wp + ((size_t)((ct * 4 + s) * 64 + lane)) * 8);
            #pragma unroll
            for (int rt = 0; rt < 2; ++rt)
                acc[rt][ct] = __builtin_amdgcn_mfma_f32_16x16x32_bf16(fa[rt], fw, acc[rt][ct], 0, 0, 0);
        }
    }
}

template<int NT>
__device__ __forceinline__ void zero_acc(f32x4 (&acc)[2][NT]) {
    #pragma unroll
    for (int rt = 0; rt < 2; ++rt)
        #pragma unroll
        for (int ct = 0; ct < NT; ++ct) acc[rt][ct] = (f32x4){0.f, 0.f, 0.f, 0.f};
}

// epilogue -> LDS (BN fold optional, ReLU always here)
template<bool BN_>
__device__ __forceinline__ void epi_to_lds(__bf16* sA, int wv, int lane, f32x4 (&acc)[2][8],
        const float* __restrict__ b, const float* __restrict__ g,
        const float* __restrict__ bb, const float* __restrict__ m,
        const float* __restrict__ v) {
    const int m0 = lane & 15, kq = lane >> 4;
    float S[8], T[8];
    #pragma unroll
    for (int ct = 0; ct < 8; ++ct) {
        int col = ct * 16 + m0;
        float bias = b[col];
        if (BN_) {
            float gg = g[col], be = bb[col], mm_ = m[col], vv = v[col];
            float s_ = gg * rsqrtf(vv + 1e-5f);
            S[ct] = s_; T[ct] = bias * s_ + (be - mm_ * s_);
        } else { S[ct] = 1.f; T[ct] = bias; }
    }
    // C/D layout: col = lane&15, row = (lane>>4)*4 + reg   [m89]
    #pragma unroll
    for (int rt = 0; rt < 2; ++rt)
        #pragma unroll
        for (int r = 0; r < 4; ++r) {
            int rl = wv * 32 + rt * 16 + kq * 4 + r;
            #pragma unroll
            for (int ct = 0; ct < 8; ++ct) {
                int col = ct * 16 + m0;
                float val = acc[rt][ct][r] * S[ct] + T[ct];
                val = fmaxf(val, 0.f);
                sA[rl * 128 + (((col >> 3) ^ (rl & 7)) << 3) + (col & 7)] = (__bf16)val;
            }
        }
}

template<int NT, bool RELU_, bool F32OUT>
__device__ __forceinline__ void epi_to_global(int wv, int lane, int rowBase, int M,
        f32x4 (&acc)[2][NT], const float* __restrict__ bias, void* outp) {
    const int m0 = lane & 15, kq = lane >> 4;
    float T[NT];
    #pragma unroll
    for (int ct = 0; ct < NT; ++ct) T[ct] = bias[ct * 16 + m0];
    #pragma unroll
    for (int rt = 0; rt < 2; ++rt)
        #pragma unroll
        for (int r = 0; r < 4; ++r) {
            int row = rowBase + wv * 32 + rt * 16 + kq * 4 + r;
            if (row < M) {
                #pragma unroll
                for (int ct = 0; ct < NT; ++ct) {
                    int col = ct * 16 + m0;
                    float val = acc[rt][ct][r] + T[ct];
                    if (RELU_) val = fmaxf(val, 0.f);
                    if (F32OUT) ((float*)outp)[(size_t)row * (NT * 16) + col] = val;
                    else        ((__bf16*)outp)[(size_t)row * (NT * 16) + col] = (__bf16)val;
                }
            }
        }
}

struct LP {   // per-stage bias/BN param sets
    const float *b0, *g0, *bb0, *m0, *v0;   // stage0: BN+ReLU
    const float *b1;                        // stage1: bias+ReLU
    const float *b2, *g2, *bb2, *m2, *v2;   // stage2: BN+ReLU (4-stage) or plain bias (3-stage)
    const float *b3;                        // stage3: plain bias (4-stage)
};

// ---- fused GIN layer chain ----
// MODE: A_AGG   A[r] = X[r] + sum_{j in adj} X[j]
//       A_PAIR  A[r] = h(r) + sum_{j in adj} h(j), h(x) = X[p0[x]] + X[p1[x]]
// NSTAGES: 2 = GIN (out bf16, ReLU)
//          3 = GIN + 128->64 projection (out f32, plain)
//          4 = GIN + 2-layer MLP (out bf16, plain)
// Block = 256 threads (4 waves), 128 rows; each wave owns a 32-row slab of sA.
// Barrier-free: gather -> stage chain all same-wave (in-order DS = RAW safe).
// Register policy: __launch_bounds__(256, 3) = min 3 waves/EU (12 waves/CU,
// matching the LDS-capped occupancy rounds 2/4 actually achieved) -> VGPR
// budget ~128+ so the 24-deep gather prefetch stays in registers instead of
// being serialized (round 4: 64-reg squeeze) or spilled (round 3).
template<int MODE, int NSTAGES>
__launch_bounds__(256, 3)
__global__ void k_layer(const __bf16* __restrict__ X, int M,
                        const int* __restrict__ offs, const int* __restrict__ cnt,
                        const int* __restrict__ adj, const int* __restrict__ pairs,
                        const __bf16* __restrict__ W0, const __bf16* __restrict__ W1,
                        const __bf16* __restrict__ W2, const __bf16* __restrict__ W3,
                        LP lp, void* __restrict__ outp) {
    __shared__ __bf16 sA[128 * 128];

    const int tid  = threadIdx.x;
    const int lane = tid & 63;
    const int wv   = tid >> 6;
    const int rowBase = blockIdx.x * 128;

    // ---- gather-aggregate phase (wave-private 32 rows; 24 loads in flight) ----
    {
        const int c    = lane & 15;       // 16B chunk of the row
        const int slot = lane >> 4;       // 4 rows per pass
        const int rb   = rowBase + wv * 32;
        int sarr[8], narr[8];
        #pragma unroll
        for (int p = 0; p < 8; ++p) {
            int grow = rb + p * 4 + slot;
            int g = grow < M ? grow : 0;
            sarr[p] = offs[g];
            narr[p] = grow < M ? cnt[g] : 0;
        }
        int pa0[8], pa1[8];               // first two neighbors of each row
        #pragma unroll
        for (int p = 0; p < 8; ++p) {
            pa0[p] = narr[p] > 0 ? adj[sarr[p]]     : 0;
            pa1[p] = narr[p] > 1 ? adj[sarr[p] + 1] : 0;
        }

        if (MODE == A_AGG) {
            int pa2[8], pa3[8];           // neighbors 2,3: index prefetch kills the
            #pragma unroll                // dependent adj->row chain for deg<=4 (~95%)
            for (int p = 0; p < 8; ++p) {
                pa2[p] = narr[p] > 2 ? adj[sarr[p] + 2] : 0;
                pa3[p] = narr[p] > 3 ? adj[sarr[p] + 3] : 0;
            }
            bf8_t sv[8], n0[8], n1[8];    // 24 row-loads issued before any use
            #pragma unroll
            for (int p = 0; p < 8; ++p) {
                int grow = rb + p * 4 + slot;
                int g = grow < M ? grow : 0;
                sv[p] = *((const bf8_t*)(X + (size_t)g * 128) + c);
            }
            #pragma unroll
            for (int p = 0; p < 8; ++p) n0[p] = *((const bf8_t*)(X + (size_t)pa0[p] * 128) + c);
            #pragma unroll
            for (int p = 0; p < 8; ++p) n1[p] = *((const bf8_t*)(X + (size_t)pa1[p] * 128) + c);
            #pragma unroll
            for (int p = 0; p < 8; ++p) {
                int rl = wv * 32 + p * 4 + slot;
                int n = narr[p];
                float a[8];
                #pragma unroll
                for (int j = 0; j < 8; ++j) {
                    float t = (float)sv[p][j];
                    if (n > 0) t += (float)n0[p][j];
                    if (n > 1) t += (float)n1[p][j];
                    a[j] = t;
                }
                if (n > 2) {
                    bf8_t v2 = *((const bf8_t*)(X + (size_t)pa2[p] * 128) + c);
                    bf8_t v3 = *((const bf8_t*)(X + (size_t)pa3[p] * 128) + c);
                    #pragma unroll
                    for (int j = 0; j < 8; ++j) a[j] += (float)v2[j];
                    if (n > 3) {
                        #pragma unroll
                        for (int j = 0; j < 8; ++j) a[j] += (float)v3[j];
                    }
                }
                int s = sarr[p], k = 4;
                for (; k + 2 <= n; k += 2) {
                    int a0 = adj[s + k], a1 = adj[s + k + 1];
                    bf8_t v0 = *((const bf8_t*)(X + (size_t)a0 * 128) + c);
                    bf8_t v1 = *((const bf8_t*)(X + (size_t)a1 * 128) + c);
                    #pragma unroll
                    for (int j = 0; j < 8; ++j) a[j] += (float)v0[j] + (float)v1[j];
                }
                if (k < n) {
                    int a0 = adj[s + k];
                    bf8_t v0 = *((const bf8_t*)(X + (size_t)a0 * 128) + c);
                    #pragma unroll
                    for (int j = 0; j < 8; ++j) a[j] += (float)v0[j];
                }
                bf8_t o;
                #pragma unroll
                for (int j = 0; j < 8; ++j) o[j] = (__bf16)a[j];
                *(bf8_t*)&sA[rl * 128 + ((c ^ (rl & 7)) << 3)] = o;
            }
        } else {                          // A_PAIR: h(x) = X[p0[x]] + X[p1[x]]
            #pragma unroll
            for (int half = 0; half < 2; ++half) {
                int2 spr[4], pq0[4], pq1[4];
                #pragma unroll
                for (int q = 0; q < 4; ++q) {
                    int p = half * 4 + q;
                    int grow = rb + p * 4 + slot;
                    int g = grow < M ? grow : 0;
                    spr[q] = ((const int2*)pairs)[g];
                    pq0[q] = ((const int2*)pairs)[pa0[p]];
                    pq1[q] = ((const int2*)pairs)[pa1[p]];
                }
                bf8_t s0[4], s1[4], u0[4], u1[4], u2[4], u3[4];   // 24 in flight
                #pragma unroll
                for (int q = 0; q < 4; ++q) {
                    s0[q] = *((const bf8_t*)(X + (size_t)spr[q].x * 128) + c);
                    s1[q] = *((const bf8_t*)(X + (size_t)spr[q].y * 128) + c);
                }
                #pragma unroll
                for (int q = 0; q < 4; ++q) {
                    u0[q] = *((const bf8_t*)(X + (size_t)pq0[q].x * 128) + c);
                    u1[q] = *((const bf8_t*)(X + (size_t)pq0[q].y * 128) + c);
                }
                #pragma unroll
                for (int q = 0; q < 4; ++q) {
                    u2[q] = *((const bf8_t*)(X + (size_t)pq1[q].x * 128) + c);
                    u3[q] = *((const bf8_t*)(X + (size_t)pq1[q].y * 128) + c);
                }
                #pragma unroll
                for (int q = 0; q < 4; ++q) {
                    int p = half * 4 + q;
                    int rl = wv * 32 + p * 4 + slot;
                    int n = narr[p];
                    float a[8];
                    #pragma unroll
                    for (int j = 0; j < 8; ++j) {
                        float t = (float)s0[q][j] + (float)s1[q][j];
                        if (n > 0) t += (float)u0[q][j] + (float)u1[q][j];
                        if (n > 1) t += (float)u2[q][j] + (float)u3[q][j];
                        a[j] = t;
                    }
                    int s = sarr[p];
                    for (int k = 2; k < n; ++k) {
                        int a0 = adj[s + k];
                        int2 qq = ((const int2*)pairs)[a0];
                        bf8_t w0 = *((const bf8_t*)(X + (size_t)qq.x * 128) + c);
                        bf8_t w1 = *((const bf8_t*)(X + (size_t)qq.y * 128) + c);
                        #pragma unroll
                        for (int j = 0; j < 8; ++j) a[j] += (float)w0[j] + (float)w1[j];
                    }
                    bf8_t o;
                    #pragma unroll
                    for (int j = 0; j < 8; ++j) o[j] = (__bf16)a[j];
                    *(bf8_t*)&sA[rl * 128 + ((c ^ (rl & 7)) << 3)] = o;
                }
            }
        }
    }

    // ---- stage 0: A @ W0, BN+ReLU -> sA ----
    f32x4 acc[2][8];
    zero_acc<8>(acc);
    mm_from_lds<8>(sA, W0, wv, lane, acc);
    epi_to_lds<true>(sA, wv, lane, acc, lp.b0, lp.g0, lp.bb0, lp.m0, lp.v0);

    // ---- stage 1: H @ W1 ----
    zero_acc<8>(acc);
    mm_from_lds<8>(sA, W1, wv, lane, acc);
    if constexpr (NSTAGES == 2) {
        epi_to_global<8, true, false>(wv, lane, rowBase, M, acc, lp.b1, outp);
    } else {
        epi_to_lds<false>(sA, wv, lane, acc, lp.b1, nullptr, nullptr, nullptr, nullptr);
        if constexpr (NSTAGES == 4) {
            // ---- stage 2: MLP layer 1 (BN+ReLU) ----
            zero_acc<8>(acc);
            mm_from_lds<8>(sA, W2, wv, lane, acc);
            epi_to_lds<true>(sA, wv, lane, acc, lp.b2, lp.g2, lp.bb2, lp.m2, lp.v2);
            // ---- stage 3: MLP layer 2 (plain) -> bf16 ----
            zero_acc<8>(acc);
            mm_from_lds<8>(sA, W3, wv, lane, acc);
            epi_to_global<8, false, false>(wv, lane, rowBase, M, acc, lp.b3, outp);
        } else {
            // ---- stage 2: 128->64 output projection (plain) -> f32 ----
            f32x4 acc3[2][4];
            zero_acc<4>(acc3);
            mm_from_lds<4>(sA, W2, wv, lane, acc3);
            epi_to_global<4, false, true>(wv, lane, rowBase, M, acc3, lp.b2, outp);
        }
    }
}

extern "C" void kernel_launch(void* const* d_in, const int* in_sizes, int n_in,
                              void* d_out, int out_size, void* d_ws, size_t ws_size,
                              hipStream_t stream) {
    const int*   edge_index = (const int*)d_in[0];     // [2, E_LINE]
    const float* x_orig     = (const float*)d_in[1];   // [N_NODES, 128] f32
    const int*   eio        = (const int*)d_in[2];     // [2, E_ORIG]
    const int*   pairs      = (const int*)d_in[3];     // [E_ORIG, 2]
    const float* iW1 = (const float*)d_in[4];
    const float* ib1 = (const float*)d_in[5];
    const float* ig  = (const float*)d_in[6];
    const float* ibb = (const float*)d_in[7];
    const float* im  = (const float*)d_in[8];
    const float* iv  = (const float*)d_in[9];
    const float* iW2 = (const float*)d_in[10];
    const float* ib2 = (const float*)d_in[11];
    const float* gW1 = (const float*)d_in[12];
    const float* gb1 = (const float*)d_in[13];
    const float* gg  = (const float*)d_in[14];
    const float* gbb = (const float*)d_in[15];
    const float* gm  = (const float*)d_in[16];
    const float* gv  = (const float*)d_in[17];
    const float* gW2 = (const float*)d_in[18];
    const float* gb2 = (const float*)d_in[19];
    const float* mW1 = (const float*)d_in[20];
    const float* mb1 = (const float*)d_in[21];
    const float* mg  = (const float*)d_in[22];
    const float* mbb = (const float*)d_in[23];
    const float* mm  = (const float*)d_in[24];
    const float* mv  = (const float*)d_in[25];
    const float* mW2 = (const float*)d_in[26];
    const float* mb2 = (const float*)d_in[27];
    const float* oW  = (const float*)d_in[28];
    const float* ob  = (const float*)d_in[29];

    // ---- workspace carve ----
    char* w = (char*)d_ws;
    __bf16* EB  = (__bf16*)w;                w += (size_t)E_ORIG * 128 * 2;   // 153.6 MB
    __bf16* XB  = (__bf16*)w;                w += (size_t)N_NODES * 128 * 2;  // 25.6 MB
    __bf16* NA  = (__bf16*)w;                w += (size_t)N_NODES * 128 * 2;  // 25.6 MB
    int* cnt  = (int*)w;                     w += (size_t)E_ORIG * 4;         // 2.4 MB
    int* offs = (int*)w;                     w += (size_t)E_ORIG * 4;         // 2.4 MB
    int* cur  = (int*)w;                     w += (size_t)E_ORIG * 4;         // 2.4 MB
    int* bsum = (int*)w;                     w += 4096 * 4;
    int* adj  = (int*)w;                     w += (size_t)E_LINE * 4;         // 4.8 MB
    __bf16* Wpk = (__bf16*)w;                /* 11 * 16384 bf16 = 352 KB */

    const int* eio_src = eio;
    const int* eio_dst = eio + E_ORIG;
    const int* el_src  = edge_index;
    const int* el_dst  = edge_index + E_LINE;

    const int nBlk = cdiv(N_NODES, 128);       // 782
    const int eBlk = cdiv(E_ORIG, 128);        // 4688
    const int nScanNB = cdiv(N_NODES, 256);    // 391
    const int eScanNB = cdiv(E_ORIG, 256);     // 2344

    // ---- pre-pack all weights to bf16 fragment-major (once per launch) ----
    WPtrs wp;
    wp.p[0] = iW1;          wp.nc[0] = 128;
    wp.p[1] = iW2;          wp.nc[1] = 128;
    wp.p[2] = iW1 + 16384;  wp.nc[2] = 128;
    wp.p[3] = iW2 + 16384;  wp.nc[3] = 128;
    wp.p[4] = mW1;          wp.nc[4] = 128;
    wp.p[5] = mW2;          wp.nc[5] = 128;
    wp.p[6] = gW1;          wp.nc[6] = 128;
    wp.p[7] = gW2;          wp.nc[7] = 128;
    wp.p[8] = gW1 + 16384;  wp.nc[8] = 128;
    wp.p[9] = gW2 + 16384;  wp.nc[9] = 128;
    wp.p[10] = oW;          wp.nc[10] = 64;
    k_packW<<<11, 256, 0, stream>>>(wp, Wpk);

    // ==== node-graph CSR (dst = eio_dst, n = N_NODES, E = E_ORIG) ====
    hipMemsetAsync(cnt, 0, (size_t)N_NODES * 4, stream);
    k_hist <<<cdiv(E_ORIG, 256), 256, 0, stream>>>(eio_dst, cnt, E_ORIG);
    k_scan1<<<nScanNB, 256, 0, stream>>>(cnt, offs, bsum, N_NODES);
    k_scan2<<<1, 256, 0, stream>>>(bsum, nScanNB);
    k_scan3<<<nScanNB, 256, 0, stream>>>(offs, cur, bsum, N_NODES);
    k_fill <<<cdiv(E_ORIG, 256), 256, 0, stream>>>(eio_src, eio_dst, cur, adj, E_ORIG);

    // ==== node stage ====
    k_f2b<<<cdiv(N_NODES * 16, 256), 256, 0, stream>>>(x_orig, XB, N_NODES * 16);

    LP lp0{};   // init GIN layer 0
    lp0.b0 = ib1;  lp0.g0 = ig;  lp0.bb0 = ibb;  lp0.m0 = im;  lp0.v0 = iv;
    lp0.b1 = ib2;
    k_layer<A_AGG, 2><<<nBlk, 256, 0, stream>>>(XB, N_NODES, offs, cnt, adj, nullptr,
        Wpk + 0 * 16384, Wpk + 1 * 16384, nullptr, nullptr, lp0, NA);

    LP lp1{};   // init GIN layer 1 + per-node MLP (4 stages) -> Y in XB
    lp1.b0 = ib1 + 128; lp1.g0 = ig + 128; lp1.bb0 = ibb + 128; lp1.m0 = im + 128; lp1.v0 = iv + 128;
    lp1.b1 = ib2 + 128;
    lp1.b2 = mb1; lp1.g2 = mg; lp1.bb2 = mbb; lp1.m2 = mm; lp1.v2 = mv;
    lp1.b3 = mb2;
    k_layer<A_AGG, 4><<<nBlk, 256, 0, stream>>>(NA, N_NODES, offs, cnt, adj, nullptr,
        Wpk + 2 * 16384, Wpk + 3 * 16384, Wpk + 4 * 16384, Wpk + 5 * 16384, lp1, XB);

    // ==== line-graph CSR (dst = el_dst, n = E_ORIG, E = E_LINE) ====
    hipMemsetAsync(cnt, 0, (size_t)E_ORIG * 4, stream);
    k_hist <<<cdiv(E_LINE, 256), 256, 0, stream>>>(el_dst, cnt, E_LINE);
    k_scan1<<<eScanNB, 256, 0, stream>>>(cnt, offs, bsum, E_ORIG);
    k_scan2<<<1, 256, 0, stream>>>(bsum, eScanNB);
    k_scan3<<<eScanNB, 256, 0, stream>>>(offs, cur, bsum, E_ORIG);
    k_fill <<<cdiv(E_LINE, 256), 256, 0, stream>>>(el_src, el_dst, cur, adj, E_LINE);

    // ==== edge stage ====
    LP lp2{};   // edge GIN layer 0 (pair-gather fused)
    lp2.b0 = gb1;  lp2.g0 = gg;  lp2.bb0 = gbb;  lp2.m0 = gm;  lp2.v0 = gv;
    lp2.b1 = gb2;
    k_layer<A_PAIR, 2><<<eBlk, 256, 0, stream>>>(XB, E_ORIG, offs, cnt, adj, pairs,
        Wpk + 6 * 16384, Wpk + 7 * 16384, nullptr, nullptr, lp2, EB);

    LP lp3{};   // edge GIN layer 1 + 128->64 output projection (3 stages) -> d_out f32
    lp3.b0 = gb1 + 128; lp3.g0 = gg + 128; lp3.bb0 = gbb + 128; lp3.m0 = gm + 128; lp3.v0 = gv + 128;
    lp3.b1 = gb2 + 128;
    lp3.b2 = ob;
    k_layer<A_AGG, 3><<<eBlk, 256, 0, stream>>>(EB, E_ORIG, offs, cnt, adj, nullptr,
        Wpk + 8 * 16384, Wpk + 9 * 16384, Wpk + 10 * 16384, nullptr, lp3, d_out);
}

// Round 7
// 1126.081 us; speedup vs baseline: 1.0619x; 1.0619x over previous
//
#include <hip/hip_runtime.h>
#include <hip/hip_bf16.h>

typedef __bf16 bf8_t __attribute__((ext_vector_type(8)));
typedef float  f32x4 __attribute__((ext_vector_type(4)));

constexpr int N_NODES = 100000;
constexpr int E_ORIG  = 600000;
constexpr int E_LINE  = 1200000;

static inline int cdiv(int a, int b) { return (a + b - 1) / b; }

enum { A_AGG = 1, A_PAIR = 2 };

// ---- f32 -> bf16 pack (x_orig once) ----
__global__ void k_f2b(const float* __restrict__ X, __bf16* __restrict__ O, int n8) {
    int i = blockIdx.x * 256 + threadIdx.x;
    if (i >= n8) return;
    float4 a = ((const float4*)X)[2 * i], b = ((const float4*)X)[2 * i + 1];
    bf8_t o;
    o[0] = (__bf16)a.x; o[1] = (__bf16)a.y; o[2] = (__bf16)a.z; o[3] = (__bf16)a.w;
    o[4] = (__bf16)b.x; o[5] = (__bf16)b.y; o[6] = (__bf16)b.z; o[7] = (__bf16)b.w;
    ((bf8_t*)O)[i] = o;
}

// ---- CSR build: histogram ----
__global__ void k_hist(const int* __restrict__ dst, int* __restrict__ cnt, int E) {
    int e = blockIdx.x * 256 + threadIdx.x;
    if (e < E) atomicAdd(&cnt[dst[e]], 1);
}

// ---- CSR build: 3-phase exclusive scan over cnt[n] ----
__global__ void k_scan1(const int* __restrict__ cnt, int* __restrict__ offs,
                        int* __restrict__ bsum, int n) {
    __shared__ int tmp[256];
    int i = blockIdx.x * 256 + threadIdx.x;
    int v = (i < n) ? cnt[i] : 0;
    tmp[threadIdx.x] = v; __syncthreads();
    #pragma unroll
    for (int d = 1; d < 256; d <<= 1) {
        int t = (threadIdx.x >= d) ? tmp[threadIdx.x - d] : 0;
        __syncthreads();
        tmp[threadIdx.x] += t;
        __syncthreads();
    }
    if (i < n) offs[i] = tmp[threadIdx.x] - v;      // exclusive within block
    if (threadIdx.x == 255) bsum[blockIdx.x] = tmp[255];
}

__global__ void k_scan2(int* __restrict__ bsum, int nb) {
    __shared__ int tmp[256];
    __shared__ int carry;
    if (threadIdx.x == 0) carry = 0;
    __syncthreads();
    for (int base = 0; base < nb; base += 256) {
        int i = base + threadIdx.x;
        int v = (i < nb) ? bsum[i] : 0;
        tmp[threadIdx.x] = v; __syncthreads();
        #pragma unroll
        for (int d = 1; d < 256; d <<= 1) {
            int t = (threadIdx.x >= d) ? tmp[threadIdx.x - d] : 0;
            __syncthreads();
            tmp[threadIdx.x] += t;
            __syncthreads();
        }
        int tot = tmp[255];
        if (i < nb) bsum[i] = tmp[threadIdx.x] - v + carry;
        __syncthreads();
        if (threadIdx.x == 0) carry += tot;
        __syncthreads();
    }
}

__global__ void k_scan3(int* __restrict__ offs, int* __restrict__ cur,
                        const int* __restrict__ bsum, int n) {
    int i = blockIdx.x * 256 + threadIdx.x;
    if (i >= n) return;
    int o = offs[i] + bsum[blockIdx.x];
    offs[i] = o;
    cur[i]  = o;
}

// ---- CSR build: bucket fill ----
__global__ void k_fill(const int* __restrict__ src, const int* __restrict__ dst,
                       int* __restrict__ cur, int* __restrict__ adj, int E) {
    int e = blockIdx.x * 256 + threadIdx.x;
    if (e >= E) return;
    int p = atomicAdd(&cur[dst[e]], 1);
    adj[p] = src[e];
}

// ---- one-time weight pre-pack: f32 [128][NC] -> bf16 fragment-major ----
// frag(c,s): lane l, elem j  <- W[k = s*32 + (l>>4)*8 + j][n = c*16 + (l&15)]
struct WPtrs { const float* p[11]; int nc[11]; };

__global__ void k_packW(WPtrs wp, __bf16* __restrict__ out) {
    const float* W = wp.p[blockIdx.x];
    const int NC = wp.nc[blockIdx.x];
    __bf16* O = out + (size_t)blockIdx.x * 16384;
    const float4* W4 = (const float4*)W;
    const int tot = 32 * NC;                       // float4 count
    for (int e = threadIdx.x; e < tot; e += 256) {
        float4 w = W4[e];
        unsigned flat = (unsigned)e * 4;
        unsigned k = flat / NC, n = flat % NC;     // 4 consecutive n share k
        unsigned c = n >> 4, s = k >> 5, hi = (k >> 3) & 3, j = k & 7;
        unsigned l0 = (hi << 4) | (n & 15);
        unsigned base = ((c * 4 + s) * 64 + l0) * 8 + j;
        O[base]      = (__bf16)w.x;
        O[base + 8]  = (__bf16)w.y;
        O[base + 16] = (__bf16)w.z;
        O[base + 24] = (__bf16)w.w;
    }
}

// ============ fused multi-stage GIN layer building blocks ============
// sA: [64][128] bf16, swizzle: element col of row rl lives at
//     rl*128 + (((col>>3) ^ (rl&7))<<3) + (col&7)

template<int NT>
__device__ __forceinline__ void mm_from_lds(const __bf16* sA, const __bf16* __restrict__ Wp,
                                            int wv, int lane, f32x4 (&acc)[2][NT]) {
    const int m0 = lane & 15, kq = lane >> 4;
    #pragma unroll
    for (int s = 0; s < 4; ++s) {
        bf8_t fa[2];
        #pragma unroll
        for (int rt = 0; rt < 2; ++rt) {
            int rl = wv * 32 + rt * 16 + m0;
            int chunk = s * 4 + kq;
            fa[rt] = *(const bf8_t*)&sA[rl * 128 + ((chunk ^ (rl & 7)) << 3)];
        }
        #pragma unroll
        for (int ct = 0; ct < NT; ++ct) {
            bf8_t fw = *(const bf8_t*)(Wp + ((size_t)((ct * 4 + s) * 64 + lane)) * 8);
            #pragma unroll
            for (int rt = 0; rt < 2; ++rt)
                acc[rt][ct] = __builtin_amdgcn_mfma_f32_16x16x32_bf16(fa[rt], fw, acc[rt][ct], 0, 0, 0);
        }
    }
}

template<int NT>
__device__ __forceinline__ void zero_acc(f32x4 (&acc)[2][NT]) {
    #pragma unroll
    for (int rt = 0; rt < 2; ++rt)
        #pragma unroll
        for (int ct = 0; ct < NT; ++ct) acc[rt][ct] = (f32x4){0.f, 0.f, 0.f, 0.f};
}

// epilogue -> LDS (BN fold optional, ReLU always here)
template<bool BN_>
__device__ __forceinline__ void epi_to_lds(__bf16* sA, int wv, int lane, f32x4 (&acc)[2][8],
        const float* __restrict__ b, const float* __restrict__ g,
        const float* __restrict__ bb, const float* __restrict__ m,
        const float* __restrict__ v) {
    const int m0 = lane & 15, kq = lane >> 4;
    float S[8], T[8];
    #pragma unroll
    for (int ct = 0; ct < 8; ++ct) {
        int col = ct * 16 + m0;
        float bias = b[col];
        if (BN_) {
            float gg = g[col], be = bb[col], mm_ = m[col], vv = v[col];
            float s_ = gg * rsqrtf(vv + 1e-5f);
            S[ct] = s_; T[ct] = bias * s_ + (be - mm_ * s_);
        } else { S[ct] = 1.f; T[ct] = bias; }
    }
    // C/D layout: col = lane&15, row = (lane>>4)*4 + reg   [m89]
    #pragma unroll
    for (int rt = 0; rt < 2; ++rt)
        #pragma unroll
        for (int r = 0; r < 4; ++r) {
            int rl = wv * 32 + rt * 16 + kq * 4 + r;
            #pragma unroll
            for (int ct = 0; ct < 8; ++ct) {
                int col = ct * 16 + m0;
                float val = acc[rt][ct][r] * S[ct] + T[ct];
                val = fmaxf(val, 0.f);
                sA[rl * 128 + (((col >> 3) ^ (rl & 7)) << 3) + (col & 7)] = (__bf16)val;
            }
        }
}

template<int NT, bool RELU_, bool F32OUT>
__device__ __forceinline__ void epi_to_global(int wv, int lane, int rowBase, int M,
        f32x4 (&acc)[2][NT], const float* __restrict__ bias, void* outp) {
    const int m0 = lane & 15, kq = lane >> 4;
    float T[NT];
    #pragma unroll
    for (int ct = 0; ct < NT; ++ct) T[ct] = bias[ct * 16 + m0];
    #pragma unroll
    for (int rt = 0; rt < 2; ++rt)
        #pragma unroll
        for (int r = 0; r < 4; ++r) {
            int row = rowBase + wv * 32 + rt * 16 + kq * 4 + r;
            if (row < M) {
                #pragma unroll
                for (int ct = 0; ct < NT; ++ct) {
                    int col = ct * 16 + m0;
                    float val = acc[rt][ct][r] + T[ct];
                    if (RELU_) val = fmaxf(val, 0.f);
                    if (F32OUT) ((float*)outp)[(size_t)row * (NT * 16) + col] = val;
                    else        ((__bf16*)outp)[(size_t)row * (NT * 16) + col] = (__bf16)val;
                }
            }
        }
}

struct LP {   // per-stage bias/BN param sets
    const float *b0, *g0, *bb0, *m0, *v0;   // stage0: BN+ReLU
    const float *b1;                        // stage1: bias+ReLU
    const float *b2, *g2, *bb2, *m2, *v2;   // stage2: BN+ReLU (4-stage) or plain bias (3-stage)
    const float *b3;                        // stage3: plain bias (4-stage)
};

// ---- fused GIN layer chain ----
// MODE: A_AGG   A[r] = X[r] + sum_{j in adj} X[j]
//       A_PAIR  A[r] = h(r) + sum_{j in adj} h(j), h(x) = X[p0[x]] + X[p1[x]]
// NSTAGES: 2 = GIN (out bf16, ReLU)
//          3 = GIN + 128->64 projection (out f32, plain)
//          4 = GIN + 2-layer MLP (out bf16, plain)
// Block = 128 threads (2 waves), 64 rows, sA = 16 KB -> LDS allows 10 blocks/CU
// (20 waves, 62%) vs 32 KB/5 blocks at 256 threads. Gather is the round-2
// PROVEN 12-loads-in-flight shape (64-84 VGPR, zero spill). Rounds 3/5/6
// showed 24-deep prefetch ALWAYS spills (+130-170 MB scratch traffic) --
// occupancy, not per-thread ILP, is the remaining latency-hiding lever.
// Barrier-free: gather -> stage chain all same-wave (in-order DS = RAW safe).
template<int MODE, int NSTAGES>
__launch_bounds__(128, 4)
__global__ void k_layer(const __bf16* __restrict__ X, int M,
                        const int* __restrict__ offs, const int* __restrict__ cnt,
                        const int* __restrict__ adj, const int* __restrict__ pairs,
                        const __bf16* __restrict__ W0, const __bf16* __restrict__ W1,
                        const __bf16* __restrict__ W2, const __bf16* __restrict__ W3,
                        LP lp, void* __restrict__ outp) {
    __shared__ __bf16 sA[64 * 128];

    const int tid  = threadIdx.x;
    const int lane = tid & 63;
    const int wv   = tid >> 6;
    const int rowBase = blockIdx.x * 64;

    // ---- gather-aggregate phase (wave-private 32 rows; 12 loads in flight) ----
    {
        const int c    = lane & 15;       // 16B chunk of the row
        const int slot = lane >> 4;       // 4 rows in flight per pass
        const int rb   = rowBase + wv * 32;
        int sarr[8], narr[8];
        #pragma unroll
        for (int p = 0; p < 8; ++p) {
            int grow = rb + p * 4 + slot;
            int g = grow < M ? grow : 0;
            sarr[p] = offs[g];
            narr[p] = grow < M ? cnt[g] : 0;
        }
        int pa0[8], pa1[8];               // first two neighbors of each row
        #pragma unroll
        for (int p = 0; p < 8; ++p) {
            pa0[p] = narr[p] > 0 ? adj[sarr[p]]     : 0;
            pa1[p] = narr[p] > 1 ? adj[sarr[p] + 1] : 0;
        }

        if (MODE == A_AGG) {
            #pragma unroll
            for (int half = 0; half < 2; ++half) {
                bf8_t sv[4], n0[4], n1[4];
                #pragma unroll
                for (int q = 0; q < 4; ++q) {
                    int p = half * 4 + q;
                    int grow = rb + p * 4 + slot;
                    int g = grow < M ? grow : 0;
                    sv[q] = *((const bf8_t*)(X + (size_t)g      * 128) + c);
                    n0[q] = *((const bf8_t*)(X + (size_t)pa0[p] * 128) + c);
                    n1[q] = *((const bf8_t*)(X + (size_t)pa1[p] * 128) + c);
                }
                #pragma unroll
                for (int q = 0; q < 4; ++q) {
                    int p = half * 4 + q;
                    int rl = wv * 32 + p * 4 + slot;
                    int n = narr[p];
                    float a[8];
                    #pragma unroll
                    for (int j = 0; j < 8; ++j) {
                        float t = (float)sv[q][j];
                        if (n > 0) t += (float)n0[q][j];
                        if (n > 1) t += (float)n1[q][j];
                        a[j] = t;
                    }
                    int s = sarr[p], k = 2;
                    for (; k + 2 <= n; k += 2) {
                        int a0 = adj[s + k], a1 = adj[s + k + 1];
                        bf8_t v0 = *((const bf8_t*)(X + (size_t)a0 * 128) + c);
                        bf8_t v1 = *((const bf8_t*)(X + (size_t)a1 * 128) + c);
                        #pragma unroll
                        for (int j = 0; j < 8; ++j) a[j] += (float)v0[j] + (float)v1[j];
                    }
                    if (k < n) {
                        int a0 = adj[s + k];
                        bf8_t v0 = *((const bf8_t*)(X + (size_t)a0 * 128) + c);
                        #pragma unroll
                        for (int j = 0; j < 8; ++j) a[j] += (float)v0[j];
                    }
                    bf8_t o;
                    #pragma unroll
                    for (int j = 0; j < 8; ++j) o[j] = (__bf16)a[j];
                    *(bf8_t*)&sA[rl * 128 + ((c ^ (rl & 7)) << 3)] = o;
                }
            }
        } else {                          // A_PAIR: h(x) = X[p0[x]] + X[p1[x]]
            #pragma unroll
            for (int half = 0; half < 2; ++half) {
                int2 spr[4], pq0[4], pq1[4];
                #pragma unroll
                for (int q = 0; q < 4; ++q) {
                    int p = half * 4 + q;
                    int grow = rb + p * 4 + slot;
                    int g = grow < M ? grow : 0;
                    spr[q] = ((const int2*)pairs)[g];
                    pq0[q] = ((const int2*)pairs)[pa0[p]];
                    pq1[q] = ((const int2*)pairs)[pa1[p]];
                }
                #pragma unroll
                for (int q = 0; q < 4; ++q) {
                    int p = half * 4 + q;
                    int rl = wv * 32 + p * 4 + slot;
                    int n = narr[p];
                    bf8_t s0 = *((const bf8_t*)(X + (size_t)spr[q].x * 128) + c);
                    bf8_t s1 = *((const bf8_t*)(X + (size_t)spr[q].y * 128) + c);
                    bf8_t u0 = *((const bf8_t*)(X + (size_t)pq0[q].x * 128) + c);
                    bf8_t u1 = *((const bf8_t*)(X + (size_t)pq0[q].y * 128) + c);
                    bf8_t u2 = *((const bf8_t*)(X + (size_t)pq1[q].x * 128) + c);
                    bf8_t u3 = *((const bf8_t*)(X + (size_t)pq1[q].y * 128) + c);
                    float a[8];
                    #pragma unroll
                    for (int j = 0; j < 8; ++j) {
                        float t = (float)s0[j] + (float)s1[j];
                        if (n > 0) t += (float)u0[j] + (float)u1[j];
                        if (n > 1) t += (float)u2[j] + (float)u3[j];
                        a[j] = t;
                    }
                    int s = sarr[p];
                    for (int k = 2; k < n; ++k) {
                        int a0 = adj[s + k];
                        int2 qq = ((const int2*)pairs)[a0];
                        bf8_t w0 = *((const bf8_t*)(X + (size_t)qq.x * 128) + c);
                        bf8_t w1 = *((const bf8_t*)(X + (size_t)qq.y * 128) + c);
                        #pragma unroll
                        for (int j = 0; j < 8; ++j) a[j] += (float)w0[j] + (float)w1[j];
                    }
                    bf8_t o;
                    #pragma unroll
                    for (int j = 0; j < 8; ++j) o[j] = (__bf16)a[j];
                    *(bf8_t*)&sA[rl * 128 + ((c ^ (rl & 7)) << 3)] = o;
                }
            }
        }
    }

    // ---- stage 0: A @ W0, BN+ReLU -> sA ----
    f32x4 acc[2][8];
    zero_acc<8>(acc);
    mm_from_lds<8>(sA, W0, wv, lane, acc);
    epi_to_lds<true>(sA, wv, lane, acc, lp.b0, lp.g0, lp.bb0, lp.m0, lp.v0);

    // ---- stage 1: H @ W1 ----
    zero_acc<8>(acc);
    mm_from_lds<8>(sA, W1, wv, lane, acc);
    if constexpr (NSTAGES == 2) {
        epi_to_global<8, true, false>(wv, lane, rowBase, M, acc, lp.b1, outp);
    } else {
        epi_to_lds<false>(sA, wv, lane, acc, lp.b1, nullptr, nullptr, nullptr, nullptr);
        if constexpr (NSTAGES == 4) {
            // ---- stage 2: MLP layer 1 (BN+ReLU) ----
            zero_acc<8>(acc);
            mm_from_lds<8>(sA, W2, wv, lane, acc);
            epi_to_lds<true>(sA, wv, lane, acc, lp.b2, lp.g2, lp.bb2, lp.m2, lp.v2);
            // ---- stage 3: MLP layer 2 (plain) -> bf16 ----
            zero_acc<8>(acc);
            mm_from_lds<8>(sA, W3, wv, lane, acc);
            epi_to_global<8, false, false>(wv, lane, rowBase, M, acc, lp.b3, outp);
        } else {
            // ---- stage 2: 128->64 output projection (plain) -> f32 ----
            f32x4 acc3[2][4];
            zero_acc<4>(acc3);
            mm_from_lds<4>(sA, W2, wv, lane, acc3);
            epi_to_global<4, false, true>(wv, lane, rowBase, M, acc3, lp.b2, outp);
        }
    }
}

extern "C" void kernel_launch(void* const* d_in, const int* in_sizes, int n_in,
                              void* d_out, int out_size, void* d_ws, size_t ws_size,
                              hipStream_t stream) {
    const int*   edge_index = (const int*)d_in[0];     // [2, E_LINE]
    const float* x_orig     = (const float*)d_in[1];   // [N_NODES, 128] f32
    const int*   eio        = (const int*)d_in[2];     // [2, E_ORIG]
    const int*   pairs      = (const int*)d_in[3];     // [E_ORIG, 2]
    const float* iW1 = (const float*)d_in[4];
    const float* ib1 = (const float*)d_in[5];
    const float* ig  = (const float*)d_in[6];
    const float* ibb = (const float*)d_in[7];
    const float* im  = (const float*)d_in[8];
    const float* iv  = (const float*)d_in[9];
    const float* iW2 = (const float*)d_in[10];
    const float* ib2 = (const float*)d_in[11];
    const float* gW1 = (const float*)d_in[12];
    const float* gb1 = (const float*)d_in[13];
    const float* gg  = (const float*)d_in[14];
    const float* gbb = (const float*)d_in[15];
    const float* gm  = (const float*)d_in[16];
    const float* gv  = (const float*)d_in[17];
    const float* gW2 = (const float*)d_in[18];
    const float* gb2 = (const float*)d_in[19];
    const float* mW1 = (const float*)d_in[20];
    const float* mb1 = (const float*)d_in[21];
    const float* mg  = (const float*)d_in[22];
    const float* mbb = (const float*)d_in[23];
    const float* mm  = (const float*)d_in[24];
    const float* mv  = (const float*)d_in[25];
    const float* mW2 = (const float*)d_in[26];
    const float* mb2 = (const float*)d_in[27];
    const float* oW  = (const float*)d_in[28];
    const float* ob  = (const float*)d_in[29];

    // ---- workspace carve ----
    char* w = (char*)d_ws;
    __bf16* EB  = (__bf16*)w;                w += (size_t)E_ORIG * 128 * 2;   // 153.6 MB
    __bf16* XB  = (__bf16*)w;                w += (size_t)N_NODES * 128 * 2;  // 25.6 MB
    __bf16* NA  = (__bf16*)w;                w += (size_t)N_NODES * 128 * 2;  // 25.6 MB
    int* cnt  = (int*)w;                     w += (size_t)E_ORIG * 4;         // 2.4 MB
    int* offs = (int*)w;                     w += (size_t)E_ORIG * 4;         // 2.4 MB
    int* cur  = (int*)w;                     w += (size_t)E_ORIG * 4;         // 2.4 MB
    int* bsum = (int*)w;                     w += 4096 * 4;
    int* adj  = (int*)w;                     w += (size_t)E_LINE * 4;         // 4.8 MB
    __bf16* Wpk = (__bf16*)w;                /* 11 * 16384 bf16 = 352 KB */

    const int* eio_src = eio;
    const int* eio_dst = eio + E_ORIG;
    const int* el_src  = edge_index;
    const int* el_dst  = edge_index + E_LINE;

    const int nBlk = cdiv(N_NODES, 64);        // 1563
    const int eBlk = cdiv(E_ORIG, 64);         // 9375
    const int nScanNB = cdiv(N_NODES, 256);    // 391
    const int eScanNB = cdiv(E_ORIG, 256);     // 2344

    // ---- pre-pack all weights to bf16 fragment-major (once per launch) ----
    WPtrs wp;
    wp.p[0] = iW1;          wp.nc[0] = 128;
    wp.p[1] = iW2;          wp.nc[1] = 128;
    wp.p[2] = iW1 + 16384;  wp.nc[2] = 128;
    wp.p[3] = iW2 + 16384;  wp.nc[3] = 128;
    wp.p[4] = mW1;          wp.nc[4] = 128;
    wp.p[5] = mW2;          wp.nc[5] = 128;
    wp.p[6] = gW1;          wp.nc[6] = 128;
    wp.p[7] = gW2;          wp.nc[7] = 128;
    wp.p[8] = gW1 + 16384;  wp.nc[8] = 128;
    wp.p[9] = gW2 + 16384;  wp.nc[9] = 128;
    wp.p[10] = oW;          wp.nc[10] = 64;
    k_packW<<<11, 256, 0, stream>>>(wp, Wpk);

    // ==== node-graph CSR (dst = eio_dst, n = N_NODES, E = E_ORIG) ====
    hipMemsetAsync(cnt, 0, (size_t)N_NODES * 4, stream);
    k_hist <<<cdiv(E_ORIG, 256), 256, 0, stream>>>(eio_dst, cnt, E_ORIG);
    k_scan1<<<nScanNB, 256, 0, stream>>>(cnt, offs, bsum, N_NODES);
    k_scan2<<<1, 256, 0, stream>>>(bsum, nScanNB);
    k_scan3<<<nScanNB, 256, 0, stream>>>(offs, cur, bsum, N_NODES);
    k_fill <<<cdiv(E_ORIG, 256), 256, 0, stream>>>(eio_src, eio_dst, cur, adj, E_ORIG);

    // ==== node stage ====
    k_f2b<<<cdiv(N_NODES * 16, 256), 256, 0, stream>>>(x_orig, XB, N_NODES * 16);

    LP lp0{};   // init GIN layer 0
    lp0.b0 = ib1;  lp0.g0 = ig;  lp0.bb0 = ibb;  lp0.m0 = im;  lp0.v0 = iv;
    lp0.b1 = ib2;
    k_layer<A_AGG, 2><<<nBlk, 128, 0, stream>>>(XB, N_NODES, offs, cnt, adj, nullptr,
        Wpk + 0 * 16384, Wpk + 1 * 16384, nullptr, nullptr, lp0, NA);

    LP lp1{};   // init GIN layer 1 + per-node MLP (4 stages) -> Y in XB
    lp1.b0 = ib1 + 128; lp1.g0 = ig + 128; lp1.bb0 = ibb + 128; lp1.m0 = im + 128; lp1.v0 = iv + 128;
    lp1.b1 = ib2 + 128;
    lp1.b2 = mb1; lp1.g2 = mg; lp1.bb2 = mbb; lp1.m2 = mm; lp1.v2 = mv;
    lp1.b3 = mb2;
    k_layer<A_AGG, 4><<<nBlk, 128, 0, stream>>>(NA, N_NODES, offs, cnt, adj, nullptr,
        Wpk + 2 * 16384, Wpk + 3 * 16384, Wpk + 4 * 16384, Wpk + 5 * 16384, lp1, XB);

    // ==== line-graph CSR (dst = el_dst, n = E_ORIG, E = E_LINE) ====
    hipMemsetAsync(cnt, 0, (size_t)E_ORIG * 4, stream);
    k_hist <<<cdiv(E_LINE, 256), 256, 0, stream>>>(el_dst, cnt, E_LINE);
    k_scan1<<<eScanNB, 256, 0, stream>>>(cnt, offs, bsum, E_ORIG);
    k_scan2<<<1, 256, 0, stream>>>(bsum, eScanNB);
    k_scan3<<<eScanNB, 256, 0, stream>>>(offs, cur, bsum, E_ORIG);
    k_fill <<<cdiv(E_LINE, 256), 256, 0, stream>>>(el_src, el_dst, cur, adj, E_LINE);

    // ==== edge stage ====
    LP lp2{};   // edge GIN layer 0 (pair-gather fused)
    lp2.b0 = gb1;  lp2.g0 = gg;  lp2.bb0 = gbb;  lp2.m0 = gm;  lp2.v0 = gv;
    lp2.b1 = gb2;
    k_layer<A_PAIR, 2><<<eBlk, 128, 0, stream>>>(XB, E_ORIG, offs, cnt, adj, pairs,
        Wpk + 6 * 16384, Wpk + 7 * 16384, nullptr, nullptr, lp2, EB);

    LP lp3{};   // edge GIN layer 1 + 128->64 output projection (3 stages) -> d_out f32
    lp3.b0 = gb1 + 128; lp3.g0 = gg + 128; lp3.bb0 = gbb + 128; lp3.m0 = gm + 128; lp3.v0 = gv + 128;
    lp3.b1 = gb2 + 128;
    lp3.b2 = ob;
    k_layer<A_AGG, 3><<<eBlk, 128, 0, stream>>>(EB, E_ORIG, offs, cnt, adj, nullptr,
        Wpk + 8 * 16384, Wpk + 9 * 16384, Wpk + 10 * 16384, nullptr, lp3, d_out);
}

// Round 8
// 1098.963 us; speedup vs baseline: 1.0881x; 1.0247x over previous
//
#include <hip/hip_runtime.h>
#include <hip/hip_bf16.h>

typedef __bf16 bf8_t __attribute__((ext_vector_type(8)));
typedef float  f32x4 __attribute__((ext_vector_type(4)));

constexpr int N_NODES = 100000;
constexpr int E_ORIG  = 600000;
constexpr int E_LINE  = 1200000;

static inline int cdiv(int a, int b) { return (a + b - 1) / b; }

enum { A_AGG = 1, A_PAIR = 2 };

// ---- f32 -> bf16 pack (x_orig once) ----
__global__ void k_f2b(const float* __restrict__ X, __bf16* __restrict__ O, int n8) {
    int i = blockIdx.x * 256 + threadIdx.x;
    if (i >= n8) return;
    float4 a = ((const float4*)X)[2 * i], b = ((const float4*)X)[2 * i + 1];
    bf8_t o;
    o[0] = (__bf16)a.x; o[1] = (__bf16)a.y; o[2] = (__bf16)a.z; o[3] = (__bf16)a.w;
    o[4] = (__bf16)b.x; o[5] = (__bf16)b.y; o[6] = (__bf16)b.z; o[7] = (__bf16)b.w;
    ((bf8_t*)O)[i] = o;
}

// ---- CSR build: histogram ----
__global__ void k_hist(const int* __restrict__ dst, int* __restrict__ cnt, int E) {
    int e = blockIdx.x * 256 + threadIdx.x;
    if (e < E) atomicAdd(&cnt[dst[e]], 1);
}

// ---- CSR build: 3-phase exclusive scan over cnt[n] ----
__global__ void k_scan1(const int* __restrict__ cnt, int* __restrict__ offs,
                        int* __restrict__ bsum, int n) {
    __shared__ int tmp[256];
    int i = blockIdx.x * 256 + threadIdx.x;
    int v = (i < n) ? cnt[i] : 0;
    tmp[threadIdx.x] = v; __syncthreads();
    #pragma unroll
    for (int d = 1; d < 256; d <<= 1) {
        int t = (threadIdx.x >= d) ? tmp[threadIdx.x - d] : 0;
        __syncthreads();
        tmp[threadIdx.x] += t;
        __syncthreads();
    }
    if (i < n) offs[i] = tmp[threadIdx.x] - v;      // exclusive within block
    if (threadIdx.x == 255) bsum[blockIdx.x] = tmp[255];
}

__global__ void k_scan2(int* __restrict__ bsum, int nb) {
    __shared__ int tmp[256];
    __shared__ int carry;
    if (threadIdx.x == 0) carry = 0;
    __syncthreads();
    for (int base = 0; base < nb; base += 256) {
        int i = base + threadIdx.x;
        int v = (i < nb) ? bsum[i] : 0;
        tmp[threadIdx.x] = v; __syncthreads();
        #pragma unroll
        for (int d = 1; d < 256; d <<= 1) {
            int t = (threadIdx.x >= d) ? tmp[threadIdx.x - d] : 0;
            __syncthreads();
            tmp[threadIdx.x] += t;
            __syncthreads();
        }
        int tot = tmp[255];
        if (i < nb) bsum[i] = tmp[threadIdx.x] - v + carry;
        __syncthreads();
        if (threadIdx.x == 0) carry += tot;
        __syncthreads();
    }
}

__global__ void k_scan3(int* __restrict__ offs, int* __restrict__ cur,
                        const int* __restrict__ bsum, int n) {
    int i = blockIdx.x * 256 + threadIdx.x;
    if (i >= n) return;
    int o = offs[i] + bsum[blockIdx.x];
    offs[i] = o;
    cur[i]  = o;
}

// ---- CSR build: bucket fill ----
__global__ void k_fill(const int* __restrict__ src, const int* __restrict__ dst,
                       int* __restrict__ cur, int* __restrict__ adj, int E) {
    int e = blockIdx.x * 256 + threadIdx.x;
    if (e >= E) return;
    int p = atomicAdd(&cur[dst[e]], 1);
    adj[p] = src[e];
}

// ---- one-time weight pre-pack: f32 [128][NC] -> bf16 fragment-major ----
// frag(c,s): lane l, elem j  <- W[k = s*32 + (l>>4)*8 + j][n = c*16 + (l&15)]
struct WPtrs { const float* p[11]; int nc[11]; };

__global__ void k_packW(WPtrs wp, __bf16* __restrict__ out) {
    const float* W = wp.p[blockIdx.x];
    const int NC = wp.nc[blockIdx.x];
    __bf16* O = out + (size_t)blockIdx.x * 16384;
    const float4* W4 = (const float4*)W;
    const int tot = 32 * NC;                       // float4 count
    for (int e = threadIdx.x; e < tot; e += 256) {
        float4 w = W4[e];
        unsigned flat = (unsigned)e * 4;
        unsigned k = flat / NC, n = flat % NC;     // 4 consecutive n share k
        unsigned c = n >> 4, s = k >> 5, hi = (k >> 3) & 3, j = k & 7;
        unsigned l0 = (hi << 4) | (n & 15);
        unsigned base = ((c * 4 + s) * 64 + l0) * 8 + j;
        O[base]      = (__bf16)w.x;
        O[base + 8]  = (__bf16)w.y;
        O[base + 16] = (__bf16)w.z;
        O[base + 24] = (__bf16)w.w;
    }
}

// ============ fused multi-stage GIN layer building blocks ============
// sA: [64][128] bf16, swizzle: element col of row rl lives at
//     rl*128 + (((col>>3) ^ (rl&7))<<3) + (col&7)

template<int NT>
__device__ __forceinline__ void mm_from_lds(const __bf16* sA, const __bf16* __restrict__ Wp,
                                            int wv, int lane, f32x4 (&acc)[2][NT]) {
    const int m0 = lane & 15, kq = lane >> 4;
    #pragma unroll
    for (int s = 0; s < 4; ++s) {
        bf8_t fa[2];
        #pragma unroll
        for (int rt = 0; rt < 2; ++rt) {
            int rl = wv * 32 + rt * 16 + m0;
            int chunk = s * 4 + kq;
            fa[rt] = *(const bf8_t*)&sA[rl * 128 + ((chunk ^ (rl & 7)) << 3)];
        }
        #pragma unroll
        for (int ct = 0; ct < NT; ++ct) {
            bf8_t fw = *(const bf8_t*)(Wp + ((size_t)((ct * 4 + s) * 64 + lane)) * 8);
            #pragma unroll
            for (int rt = 0; rt < 2; ++rt)
                acc[rt][ct] = __builtin_amdgcn_mfma_f32_16x16x32_bf16(fa[rt], fw, acc[rt][ct], 0, 0, 0);
        }
    }
}

template<int NT>
__device__ __forceinline__ void zero_acc(f32x4 (&acc)[2][NT]) {
    #pragma unroll
    for (int rt = 0; rt < 2; ++rt)
        #pragma unroll
        for (int ct = 0; ct < NT; ++ct) acc[rt][ct] = (f32x4){0.f, 0.f, 0.f, 0.f};
}

// epilogue -> LDS (BN fold optional, ReLU always here)
template<bool BN_>
__device__ __forceinline__ void epi_to_lds(__bf16* sA, int wv, int lane, f32x4 (&acc)[2][8],
        const float* __restrict__ b, const float* __restrict__ g,
        const float* __restrict__ bb, const float* __restrict__ m,
        const float* __restrict__ v) {
    const int m0 = lane & 15, kq = lane >> 4;
    float S[8], T[8];
    #pragma unroll
    for (int ct = 0; ct < 8; ++ct) {
        int col = ct * 16 + m0;
        float bias = b[col];
        if (BN_) {
            float gg = g[col], be = bb[col], mm_ = m[col], vv = v[col];
            float s_ = gg * rsqrtf(vv + 1e-5f);
            S[ct] = s_; T[ct] = bias * s_ + (be - mm_ * s_);
        } else { S[ct] = 1.f; T[ct] = bias; }
    }
    // C/D layout: col = lane&15, row = (lane>>4)*4 + reg   [m89]
    #pragma unroll
    for (int rt = 0; rt < 2; ++rt)
        #pragma unroll
        for (int r = 0; r < 4; ++r) {
            int rl = wv * 32 + rt * 16 + kq * 4 + r;
            #pragma unroll
            for (int ct = 0; ct < 8; ++ct) {
                int col = ct * 16 + m0;
                float val = acc[rt][ct][r] * S[ct] + T[ct];
                val = fmaxf(val, 0.f);
                sA[rl * 128 + (((col >> 3) ^ (rl & 7)) << 3) + (col & 7)] = (__bf16)val;
            }
        }
}

// F32OUT path uses NON-TEMPORAL stores: d_out (153.6 MB f32) must not allocate
// L3, or it evicts the L3-resident EB (153.6 MB) mid-dispatch and the random
// neighbor gather falls to the ~3 TB/s HBM-random ceiling (round 7: FETCH was
// 2x EB = ~150 MB of re-fetch caused by exactly this pollution).
template<int NT, bool RELU_, bool F32OUT>
__device__ __forceinline__ void epi_to_global(int wv, int lane, int rowBase, int M,
        f32x4 (&acc)[2][NT], const float* __restrict__ bias, void* outp) {
    const int m0 = lane & 15, kq = lane >> 4;
    float T[NT];
    #pragma unroll
    for (int ct = 0; ct < NT; ++ct) T[ct] = bias[ct * 16 + m0];
    #pragma unroll
    for (int rt = 0; rt < 2; ++rt)
        #pragma unroll
        for (int r = 0; r < 4; ++r) {
            int row = rowBase + wv * 32 + rt * 16 + kq * 4 + r;
            if (row < M) {
                #pragma unroll
                for (int ct = 0; ct < NT; ++ct) {
                    int col = ct * 16 + m0;
                    float val = acc[rt][ct][r] + T[ct];
                    if (RELU_) val = fmaxf(val, 0.f);
                    if (F32OUT) {
                        __builtin_nontemporal_store(val, &((float*)outp)[(size_t)row * (NT * 16) + col]);
                    } else {
                        ((__bf16*)outp)[(size_t)row * (NT * 16) + col] = (__bf16)val;
                    }
                }
            }
        }
}

struct LP {   // per-stage bias/BN param sets
    const float *b0, *g0, *bb0, *m0, *v0;   // stage0: BN+ReLU
    const float *b1;                        // stage1: bias+ReLU
    const float *b2, *g2, *bb2, *m2, *v2;   // stage2: BN+ReLU (4-stage) or plain bias (3-stage)
    const float *b3;                        // stage3: plain bias (4-stage)
};

// ---- fused GIN layer chain ----
// MODE: A_AGG   A[r] = X[r] + sum_{j in adj} X[j]
//       A_PAIR  A[r] = h(r) + sum_{j in adj} h(j), h(x) = X[p0[x]] + X[p1[x]]
// NSTAGES: 2 = GIN (out bf16, ReLU)
//          3 = GIN + 128->64 projection (out f32 NT, plain)
//          4 = GIN + 2-layer MLP (out bf16, plain)
// Block = 128 threads (2 waves), 64 rows, sA = 16 KB. Gather is the proven
// 12-loads-in-flight shape (64 VGPR, zero spill; 24-deep always spills).
// Barrier-free: gather -> stage chain all same-wave (in-order DS = RAW safe).
template<int MODE, int NSTAGES>
__launch_bounds__(128, 4)
__global__ void k_layer(const __bf16* __restrict__ X, int M,
                        const int* __restrict__ offs, const int* __restrict__ cnt,
                        const int* __restrict__ adj, const int* __restrict__ pairs,
                        const __bf16* __restrict__ W0, const __bf16* __restrict__ W1,
                        const __bf16* __restrict__ W2, const __bf16* __restrict__ W3,
                        LP lp, void* __restrict__ outp) {
    __shared__ __bf16 sA[64 * 128];

    const int tid  = threadIdx.x;
    const int lane = tid & 63;
    const int wv   = tid >> 6;
    const int rowBase = blockIdx.x * 64;

    // ---- gather-aggregate phase (wave-private 32 rows; 12 loads in flight) ----
    {
        const int c    = lane & 15;       // 16B chunk of the row
        const int slot = lane >> 4;       // 4 rows in flight per pass
        const int rb   = rowBase + wv * 32;
        int sarr[8], narr[8];
        #pragma unroll
        for (int p = 0; p < 8; ++p) {
            int grow = rb + p * 4 + slot;
            int g = grow < M ? grow : 0;
            sarr[p] = offs[g];
            narr[p] = grow < M ? cnt[g] : 0;
        }
        int pa0[8], pa1[8];               // first two neighbors of each row
        #pragma unroll
        for (int p = 0; p < 8; ++p) {
            pa0[p] = narr[p] > 0 ? adj[sarr[p]]     : 0;
            pa1[p] = narr[p] > 1 ? adj[sarr[p] + 1] : 0;
        }

        if (MODE == A_AGG) {
            #pragma unroll
            for (int half = 0; half < 2; ++half) {
                bf8_t sv[4], n0[4], n1[4];
                #pragma unroll
                for (int q = 0; q < 4; ++q) {
                    int p = half * 4 + q;
                    int grow = rb + p * 4 + slot;
                    int g = grow < M ? grow : 0;
                    sv[q] = *((const bf8_t*)(X + (size_t)g      * 128) + c);
                    n0[q] = *((const bf8_t*)(X + (size_t)pa0[p] * 128) + c);
                    n1[q] = *((const bf8_t*)(X + (size_t)pa1[p] * 128) + c);
                }
                #pragma unroll
                for (int q = 0; q < 4; ++q) {
                    int p = half * 4 + q;
                    int rl = wv * 32 + p * 4 + slot;
                    int n = narr[p];
                    float a[8];
                    #pragma unroll
                    for (int j = 0; j < 8; ++j) {
                        float t = (float)sv[q][j];
                        if (n > 0) t += (float)n0[q][j];
                        if (n > 1) t += (float)n1[q][j];
                        a[j] = t;
                    }
                    int s = sarr[p], k = 2;
                    for (; k + 2 <= n; k += 2) {
                        int a0 = adj[s + k], a1 = adj[s + k + 1];
                        bf8_t v0 = *((const bf8_t*)(X + (size_t)a0 * 128) + c);
                        bf8_t v1 = *((const bf8_t*)(X + (size_t)a1 * 128) + c);
                        #pragma unroll
                        for (int j = 0; j < 8; ++j) a[j] += (float)v0[j] + (float)v1[j];
                    }
                    if (k < n) {
                        int a0 = adj[s + k];
                        bf8_t v0 = *((const bf8_t*)(X + (size_t)a0 * 128) + c);
                        #pragma unroll
                        for (int j = 0; j < 8; ++j) a[j] += (float)v0[j];
                    }
                    bf8_t o;
                    #pragma unroll
                    for (int j = 0; j < 8; ++j) o[j] = (__bf16)a[j];
                    *(bf8_t*)&sA[rl * 128 + ((c ^ (rl & 7)) << 3)] = o;
                }
            }
        } else {                          // A_PAIR: h(x) = X[p0[x]] + X[p1[x]]
            #pragma unroll
            for (int half = 0; half < 2; ++half) {
                int2 spr[4], pq0[4], pq1[4];
                #pragma unroll
                for (int q = 0; q < 4; ++q) {
                    int p = half * 4 + q;
                    int grow = rb + p * 4 + slot;
                    int g = grow < M ? grow : 0;
                    spr[q] = ((const int2*)pairs)[g];
                    pq0[q] = ((const int2*)pairs)[pa0[p]];
                    pq1[q] = ((const int2*)pairs)[pa1[p]];
                }
                #pragma unroll
                for (int q = 0; q < 4; ++q) {
                    int p = half * 4 + q;
                    int rl = wv * 32 + p * 4 + slot;
                    int n = narr[p];
                    bf8_t s0 = *((const bf8_t*)(X + (size_t)spr[q].x * 128) + c);
                    bf8_t s1 = *((const bf8_t*)(X + (size_t)spr[q].y * 128) + c);
                    bf8_t u0 = *((const bf8_t*)(X + (size_t)pq0[q].x * 128) + c);
                    bf8_t u1 = *((const bf8_t*)(X + (size_t)pq0[q].y * 128) + c);
                    bf8_t u2 = *((const bf8_t*)(X + (size_t)pq1[q].x * 128) + c);
                    bf8_t u3 = *((const bf8_t*)(X + (size_t)pq1[q].y * 128) + c);
                    float a[8];
                    #pragma unroll
                    for (int j = 0; j < 8; ++j) {
                        float t = (float)s0[j] + (float)s1[j];
                        if (n > 0) t += (float)u0[j] + (float)u1[j];
                        if (n > 1) t += (float)u2[j] + (float)u3[j];
                        a[j] = t;
                    }
                    int s = sarr[p];
                    for (int k = 2; k < n; ++k) {
                        int a0 = adj[s + k];
                        int2 qq = ((const int2*)pairs)[a0];
                        bf8_t w0 = *((const bf8_t*)(X + (size_t)qq.x * 128) + c);
                        bf8_t w1 = *((const bf8_t*)(X + (size_t)qq.y * 128) + c);
                        #pragma unroll
                        for (int j = 0; j < 8; ++j) a[j] += (float)w0[j] + (float)w1[j];
                    }
                    bf8_t o;
                    #pragma unroll
                    for (int j = 0; j < 8; ++j) o[j] = (__bf16)a[j];
                    *(bf8_t*)&sA[rl * 128 + ((c ^ (rl & 7)) << 3)] = o;
                }
            }
        }
    }

    // ---- stage 0: A @ W0, BN+ReLU -> sA ----
    f32x4 acc[2][8];
    zero_acc<8>(acc);
    mm_from_lds<8>(sA, W0, wv, lane, acc);
    epi_to_lds<true>(sA, wv, lane, acc, lp.b0, lp.g0, lp.bb0, lp.m0, lp.v0);

    // ---- stage 1: H @ W1 ----
    zero_acc<8>(acc);
    mm_from_lds<8>(sA, W1, wv, lane, acc);
    if constexpr (NSTAGES == 2) {
        epi_to_global<8, true, false>(wv, lane, rowBase, M, acc, lp.b1, outp);
    } else {
        epi_to_lds<false>(sA, wv, lane, acc, lp.b1, nullptr, nullptr, nullptr, nullptr);
        if constexpr (NSTAGES == 4) {
            // ---- stage 2: MLP layer 1 (BN+ReLU) ----
            zero_acc<8>(acc);
            mm_from_lds<8>(sA, W2, wv, lane, acc);
            epi_to_lds<true>(sA, wv, lane, acc, lp.b2, lp.g2, lp.bb2, lp.m2, lp.v2);
            // ---- stage 3: MLP layer 2 (plain) -> bf16 ----
            zero_acc<8>(acc);
            mm_from_lds<8>(sA, W3, wv, lane, acc);
            epi_to_global<8, false, false>(wv, lane, rowBase, M, acc, lp.b3, outp);
        } else {
            // ---- stage 2: 128->64 output projection (plain) -> f32 (NT) ----
            f32x4 acc3[2][4];
            zero_acc<4>(acc3);
            mm_from_lds<4>(sA, W2, wv, lane, acc3);
            epi_to_global<4, false, true>(wv, lane, rowBase, M, acc3, lp.b2, outp);
        }
    }
}

extern "C" void kernel_launch(void* const* d_in, const int* in_sizes, int n_in,
                              void* d_out, int out_size, void* d_ws, size_t ws_size,
                              hipStream_t stream) {
    const int*   edge_index = (const int*)d_in[0];     // [2, E_LINE]
    const float* x_orig     = (const float*)d_in[1];   // [N_NODES, 128] f32
    const int*   eio        = (const int*)d_in[2];     // [2, E_ORIG]
    const int*   pairs      = (const int*)d_in[3];     // [E_ORIG, 2]
    const float* iW1 = (const float*)d_in[4];
    const float* ib1 = (const float*)d_in[5];
    const float* ig  = (const float*)d_in[6];
    const float* ibb = (const float*)d_in[7];
    const float* im  = (const float*)d_in[8];
    const float* iv  = (const float*)d_in[9];
    const float* iW2 = (const float*)d_in[10];
    const float* ib2 = (const float*)d_in[11];
    const float* gW1 = (const float*)d_in[12];
    const float* gb1 = (const float*)d_in[13];
    const float* gg  = (const float*)d_in[14];
    const float* gbb = (const float*)d_in[15];
    const float* gm  = (const float*)d_in[16];
    const float* gv  = (const float*)d_in[17];
    const float* gW2 = (const float*)d_in[18];
    const float* gb2 = (const float*)d_in[19];
    const float* mW1 = (const float*)d_in[20];
    const float* mb1 = (const float*)d_in[21];
    const float* mg  = (const float*)d_in[22];
    const float* mbb = (const float*)d_in[23];
    const float* mm  = (const float*)d_in[24];
    const float* mv  = (const float*)d_in[25];
    const float* mW2 = (const float*)d_in[26];
    const float* mb2 = (const float*)d_in[27];
    const float* oW  = (const float*)d_in[28];
    const float* ob  = (const float*)d_in[29];

    // ---- workspace carve ----
    char* w = (char*)d_ws;
    __bf16* EB  = (__bf16*)w;                w += (size_t)E_ORIG * 128 * 2;   // 153.6 MB
    __bf16* XB  = (__bf16*)w;                w += (size_t)N_NODES * 128 * 2;  // 25.6 MB
    __bf16* NA  = (__bf16*)w;                w += (size_t)N_NODES * 128 * 2;  // 25.6 MB
    int* cnt  = (int*)w;                     w += (size_t)E_ORIG * 4;         // 2.4 MB
    int* offs = (int*)w;                     w += (size_t)E_ORIG * 4;         // 2.4 MB
    int* cur  = (int*)w;                     w += (size_t)E_ORIG * 4;         // 2.4 MB
    int* bsum = (int*)w;                     w += 4096 * 4;
    int* adj  = (int*)w;                     w += (size_t)E_LINE * 4;         // 4.8 MB
    __bf16* Wpk = (__bf16*)w;                /* 11 * 16384 bf16 = 352 KB */

    const int* eio_src = eio;
    const int* eio_dst = eio + E_ORIG;
    const int* el_src  = edge_index;
    const int* el_dst  = edge_index + E_LINE;

    const int nBlk = cdiv(N_NODES, 64);        // 1563
    const int eBlk = cdiv(E_ORIG, 64);         // 9375
    const int nScanNB = cdiv(N_NODES, 256);    // 391
    const int eScanNB = cdiv(E_ORIG, 256);     // 2344

    // ---- pre-pack all weights to bf16 fragment-major (once per launch) ----
    WPtrs wp;
    wp.p[0] = iW1;          wp.nc[0] = 128;
    wp.p[1] = iW2;          wp.nc[1] = 128;
    wp.p[2] = iW1 + 16384;  wp.nc[2] = 128;
    wp.p[3] = iW2 + 16384;  wp.nc[3] = 128;
    wp.p[4] = mW1;          wp.nc[4] = 128;
    wp.p[5] = mW2;          wp.nc[5] = 128;
    wp.p[6] = gW1;          wp.nc[6] = 128;
    wp.p[7] = gW2;          wp.nc[7] = 128;
    wp.p[8] = gW1 + 16384;  wp.nc[8] = 128;
    wp.p[9] = gW2 + 16384;  wp.nc[9] = 128;
    wp.p[10] = oW;          wp.nc[10] = 64;
    k_packW<<<11, 256, 0, stream>>>(wp, Wpk);

    // ==== node-graph CSR (dst = eio_dst, n = N_NODES, E = E_ORIG) ====
    hipMemsetAsync(cnt, 0, (size_t)N_NODES * 4, stream);
    k_hist <<<cdiv(E_ORIG, 256), 256, 0, stream>>>(eio_dst, cnt, E_ORIG);
    k_scan1<<<nScanNB, 256, 0, stream>>>(cnt, offs, bsum, N_NODES);
    k_scan2<<<1, 256, 0, stream>>>(bsum, nScanNB);
    k_scan3<<<nScanNB, 256, 0, stream>>>(offs, cur, bsum, N_NODES);
    k_fill <<<cdiv(E_ORIG, 256), 256, 0, stream>>>(eio_src, eio_dst, cur, adj, E_ORIG);

    // ==== node stage ====
    k_f2b<<<cdiv(N_NODES * 16, 256), 256, 0, stream>>>(x_orig, XB, N_NODES * 16);

    LP lp0{};   // init GIN layer 0
    lp0.b0 = ib1;  lp0.g0 = ig;  lp0.bb0 = ibb;  lp0.m0 = im;  lp0.v0 = iv;
    lp0.b1 = ib2;
    k_layer<A_AGG, 2><<<nBlk, 128, 0, stream>>>(XB, N_NODES, offs, cnt, adj, nullptr,
        Wpk + 0 * 16384, Wpk + 1 * 16384, nullptr, nullptr, lp0, NA);

    LP lp1{};   // init GIN layer 1 + per-node MLP (4 stages) -> Y in XB
    lp1.b0 = ib1 + 128; lp1.g0 = ig + 128; lp1.bb0 = ibb + 128; lp1.m0 = im + 128; lp1.v0 = iv + 128;
    lp1.b1 = ib2 + 128;
    lp1.b2 = mb1; lp1.g2 = mg; lp1.bb2 = mbb; lp1.m2 = mm; lp1.v2 = mv;
    lp1.b3 = mb2;
    k_layer<A_AGG, 4><<<nBlk, 128, 0, stream>>>(NA, N_NODES, offs, cnt, adj, nullptr,
        Wpk + 2 * 16384, Wpk + 3 * 16384, Wpk + 4 * 16384, Wpk + 5 * 16384, lp1, XB);

    // ==== line-graph CSR (dst = el_dst, n = E_ORIG, E = E_LINE) ====
    hipMemsetAsync(cnt, 0, (size_t)E_ORIG * 4, stream);
    k_hist <<<cdiv(E_LINE, 256), 256, 0, stream>>>(el_dst, cnt, E_LINE);
    k_scan1<<<eScanNB, 256, 0, stream>>>(cnt, offs, bsum, E_ORIG);
    k_scan2<<<1, 256, 0, stream>>>(bsum, eScanNB);
    k_scan3<<<eScanNB, 256, 0, stream>>>(offs, cur, bsum, E_ORIG);
    k_fill <<<cdiv(E_LINE, 256), 256, 0, stream>>>(el_src, el_dst, cur, adj, E_LINE);

    // ==== edge stage ====
    LP lp2{};   // edge GIN layer 0 (pair-gather fused) -> EB (normal stores: seeds L3)
    lp2.b0 = gb1;  lp2.g0 = gg;  lp2.bb0 = gbb;  lp2.m0 = gm;  lp2.v0 = gv;
    lp2.b1 = gb2;
    k_layer<A_PAIR, 2><<<eBlk, 128, 0, stream>>>(XB, E_ORIG, offs, cnt, adj, pairs,
        Wpk + 6 * 16384, Wpk + 7 * 16384, nullptr, nullptr, lp2, EB);

    LP lp3{};   // edge GIN layer 1 + 128->64 projection (3 stages) -> d_out f32 (NT)
    lp3.b0 = gb1 + 128; lp3.g0 = gg + 128; lp3.bb0 = gbb + 128; lp3.m0 = gm + 128; lp3.v0 = gv + 128;
    lp3.b1 = gb2 + 128;
    lp3.b2 = ob;
    k_layer<A_AGG, 3><<<eBlk, 128, 0, stream>>>(EB, E_ORIG, offs, cnt, adj, nullptr,
        Wpk + 8 * 16384, Wpk + 9 * 16384, Wpk + 10 * 16384, nullptr, lp3, d_out);
}